// Round 1
// 613.483 us; speedup vs baseline: 1.4108x; 1.4108x over previous
//
#include <hip/hip_runtime.h>

#define C_N 64
#define I_N 64
#define R_N 36
#define L_N 40
#define D_N 1024
#define S_N 256

#define P_LD 72   // p row stride (shorts): 144 B, 16B-aligned rows

// ws layout (shorts):
#define OFF_CAP 2359296               // img end
#define OFF_WT  4980736               // cap end
#define OFF_IMT 5242880               // wt end: img_t [i][d][r48]
#define OFF_SLK 8126464               // img_t end: 64 zero shorts (k-overread slack)
#define OFF_SIM 8388672               // sim [pair*40 + l][1024] bf16
#define M_ALL   (C_N * I_N * L_N)

typedef float f4 __attribute__((ext_vector_type(4)));
typedef short s16x8 __attribute__((ext_vector_type(8)));
typedef short s16x4 __attribute__((ext_vector_type(4)));

__device__ __forceinline__ unsigned short f2bs(float f) {
    union { float f; unsigned u; } v; v.f = f;
    unsigned r = v.u + 0x7FFFu + ((v.u >> 16) & 1u);
    return (unsigned short)(r >> 16);
}
__device__ __forceinline__ float bs2f(unsigned short s) {
    union { unsigned u; float f; } v; v.u = ((unsigned)s) << 16;
    return v.f;
}
__device__ __forceinline__ void async16(const unsigned short* g, unsigned short* l) {
    __builtin_amdgcn_global_load_lds(
        (const __attribute__((address_space(1))) unsigned int*)g,
        (__attribute__((address_space(3))) unsigned int*)l, 16, 0, 0);
}

// ---------------- K0: converts ----------------
__global__ void k_convert(const float* __restrict__ img, const float* __restrict__ cap,
                          const float* __restrict__ W, unsigned short* __restrict__ ws) {
    int t = blockIdx.x * 256 + threadIdx.x;
    if (t < I_N * R_N * D_N) ws[t] = f2bs(img[t]);
    if (t < C_N * L_N * D_N) ws[OFF_CAP + t] = f2bs(cap[t]);
    if (t < D_N * S_N) {                       // W[d][s] -> Wt[s][d]
        int d = t >> 8, s = t & 255;
        ws[OFF_WT + s * D_N + d] = f2bs(W[t]);
    }
    if (t < I_N * R_N * D_N) {                 // img_t [i][d][r48]
        int i = t / (R_N * D_N), r = (t / D_N) % R_N, d = t % D_N;
        ws[OFF_IMT + (i * D_N + d) * 48 + r] = f2bs(img[t]);
    }
    if (t < I_N * D_N * 12) {                  // img_t zero rows 36..47
        int i = t / (D_N * 12), d = (t / 12) % D_N, rr = t % 12;
        ws[OFF_IMT + (i * D_N + d) * 48 + 36 + rr] = 0;
    }
    if (t < 64) ws[OFF_SLK + t] = 0;
}

// ---------------- A: one WAVE per (c,i): GEMM1 + softmax (in-register) + GEMM2 + sim.
// Block = 8 waves sharing image i. NO __syncthreads anywhere.
// XCD-aware remap: linear block n -> XCD n%8; each XCD gets a 4-octet x 16-image
// tile so its resident set (cap 2.56MB + img/imt 2.69MB) ~fits the 4MB L2.
__global__ __launch_bounds__(512, 4)
void k_pre(const unsigned short* __restrict__ img_b,
           const unsigned short* __restrict__ cap_b,
           const unsigned short* __restrict__ img_t,
           unsigned short* __restrict__ simg) {
    __shared__ __align__(16) unsigned short s_p[8][48 * P_LD];   // 55296 B

    const int n = blockIdx.y * 8 + blockIdx.x;       // linear id; XCD = n & 7
    const int x = n & 7, m = n >> 3;
    const int i   = ((x & 3) << 4) | (m >> 2);       // 16 images per XCD
    const int oct = ((x >> 2) << 2) | (m & 3);       // 4 octets per XCD
    const int wave = threadIdx.x >> 6, lane = threadIdx.x & 63;
    const int c = oct * 8 + wave;
    const int pair = c * I_N + i;
    const int q = lane >> 4, ln16 = lane & 15;

    const unsigned short* ai = img_b + i * (R_N * D_N);          // GEMM1 A (m=r)
    const unsigned short* bc = cap_b + c * (L_N * D_N);          // GEMM1 B (n=l), sim cap
    const unsigned short* imtc = img_t + (size_t)i * D_N * 48;   // GEMM2 A (m=d,k=r)
    unsigned short* sp = &s_p[wave][0];

    // zero own p slot (covers m-pad rows 40..47 and k-pad cols 36..71)
    for (int k = lane; k < 48 * P_LD / 2; k += 64) ((unsigned*)sp)[k] = 0;

    // ---- GEMM1: attn[r][l], full K=1024 in this wave ----
    f4 acc[3][3] = {};
    #pragma unroll 4
    for (int ks = 0; ks < 32; ++ks) {
        const int kb = ks * 32 + q * 8;
        s16x8 af[3], bf[3];
        af[0] = *(const s16x8*)(ai + ln16 * D_N + kb);
        af[1] = *(const s16x8*)(ai + (16 + ln16) * D_N + kb);
        af[2] = (ln16 < 4) ? *(const s16x8*)(ai + (32 + ln16) * D_N + kb) : (s16x8)0;
        bf[0] = *(const s16x8*)(bc + ln16 * D_N + kb);
        bf[1] = *(const s16x8*)(bc + (16 + ln16) * D_N + kb);
        bf[2] = (ln16 < 8) ? *(const s16x8*)(bc + (32 + ln16) * D_N + kb) : (s16x8)0;
        #pragma unroll
        for (int mt = 0; mt < 3; ++mt)
            #pragma unroll
            for (int nt = 0; nt < 3; ++nt)
                acc[mt][nt] = __builtin_amdgcn_mfma_f32_16x16x32_bf16(af[mt], bf[nt], acc[mt][nt], 0, 0, 0);
    }

    // ---- leaky relu (elementwise) ----
    #pragma unroll
    for (int mt = 0; mt < 3; ++mt)
        #pragma unroll
        for (int nt = 0; nt < 3; ++nt)
            #pragma unroll
            for (int j = 0; j < 4; ++j) {
                float v = acc[mt][nt][j];
                acc[mt][nt][j] = (v > 0.f) ? v : 0.1f * v;
            }
    // ---- l2norm over words l (= nt,ln16 dims) for each region row r ----
    #pragma unroll
    for (int mt = 0; mt < 3; ++mt)
        #pragma unroll
        for (int j = 0; j < 4; ++j) {
            float ss = 0.f;
            #pragma unroll
            for (int nt = 0; nt < 3; ++nt) ss += acc[mt][nt][j] * acc[mt][nt][j];
            #pragma unroll
            for (int o = 1; o < 16; o <<= 1) ss += __shfl_xor(ss, o, 64);
            float inv = 1.f / (sqrtf(ss) + 1e-8f);
            #pragma unroll
            for (int nt = 0; nt < 3; ++nt) acc[mt][nt][j] *= inv;
        }
    // ---- softmax over regions r (= mt,q,j dims) per word l; store p[l][r] to LDS ----
    #pragma unroll
    for (int nt = 0; nt < 3; ++nt) {
        const int l = nt * 16 + ln16;
        float mx = -1e30f;
        #pragma unroll
        for (int mt = 0; mt < 3; ++mt)
            #pragma unroll
            for (int j = 0; j < 4; ++j) {
                int r = mt * 16 + q * 4 + j;
                if (r < R_N) mx = fmaxf(mx, 9.f * acc[mt][nt][j]);
            }
        mx = fmaxf(mx, __shfl_xor(mx, 16, 64));
        mx = fmaxf(mx, __shfl_xor(mx, 32, 64));
        float sum = 0.f;
        #pragma unroll
        for (int mt = 0; mt < 3; ++mt)
            #pragma unroll
            for (int j = 0; j < 4; ++j) {
                int r = mt * 16 + q * 4 + j;
                float e = (r < R_N) ? __expf(9.f * acc[mt][nt][j] - mx) : 0.f;
                acc[mt][nt][j] = e;
                sum += e;
            }
        sum += __shfl_xor(sum, 16, 64);
        sum += __shfl_xor(sum, 32, 64);
        float inv = 1.f / sum;
        #pragma unroll
        for (int mt = 0; mt < 3; ++mt)
            #pragma unroll
            for (int j = 0; j < 4; ++j) {
                int r = mt * 16 + q * 4 + j;
                if (r < R_N && l < L_N) sp[l * P_LD + r] = f2bs(acc[mt][nt][j] * inv);
            }
    }
    // same-wave DS ops complete in order; reads below see the writes (no barrier).

    // ---- GEMM2 p-fragments once: used as B operand [n=l][k=r] ----
    s16x8 paf[3][2];
    #pragma unroll
    for (int nl = 0; nl < 3; ++nl)
        #pragma unroll
        for (int ks = 0; ks < 2; ++ks)
            paf[nl][ks] = *(const s16x8*)(sp + (nl * 16 + ln16) * P_LD + ks * 32 + q * 8);

    // ---- GEMM2 pass 1 (operands SWAPPED: A=imt rows d, B=p rows l) ----
    // C layout: row (q*4+j) = d (4 consecutive per lane!), col ln16 = l.
    float rs[3] = {};
    #pragma unroll 2
    for (int ch = 0; ch < 32; ++ch) {
        f4 a2[2][3] = {};
        #pragma unroll
        for (int ks = 0; ks < 2; ++ks) {
            const int kb = ks * 32 + q * 8;
            #pragma unroll
            for (int md = 0; md < 2; ++md) {
                const int drow = ch * 32 + md * 16 + ln16;
                s16x8 afr = *(const s16x8*)(imtc + drow * 48 + kb);
                #pragma unroll
                for (int nl = 0; nl < 3; ++nl)
                    a2[md][nl] = __builtin_amdgcn_mfma_f32_16x16x32_bf16(afr, paf[nl][ks], a2[md][nl], 0, 0, 0);
            }
        }
        #pragma unroll
        for (int md = 0; md < 2; ++md)
            #pragma unroll
            for (int nl = 0; nl < 3; ++nl)
                #pragma unroll
                for (int j = 0; j < 4; ++j)
                    rs[nl] += a2[md][nl][j] * a2[md][nl][j];
    }
    float inv2[3];
    #pragma unroll
    for (int nl = 0; nl < 3; ++nl) {
        float s = rs[nl];
        s += __shfl_xor(s, 16, 64);
        s += __shfl_xor(s, 32, 64);
        inv2[nl] = 1.f / (sqrtf(s) + 1e-8f);
    }

    // ---- GEMM2 pass 2: recompute wc, sim=(wc*inv-cap)^2 -> global bf16 (8B nt stores) ----
    unsigned short* so = simg + (size_t)pair * L_N * D_N;
    #pragma unroll 2
    for (int ch = 0; ch < 32; ++ch) {
        f4 a2[2][3] = {};
        #pragma unroll
        for (int ks = 0; ks < 2; ++ks) {
            const int kb = ks * 32 + q * 8;
            #pragma unroll
            for (int md = 0; md < 2; ++md) {
                const int drow = ch * 32 + md * 16 + ln16;
                s16x8 afr = *(const s16x8*)(imtc + drow * 48 + kb);
                #pragma unroll
                for (int nl = 0; nl < 3; ++nl)
                    a2[md][nl] = __builtin_amdgcn_mfma_f32_16x16x32_bf16(afr, paf[nl][ks], a2[md][nl], 0, 0, 0);
            }
        }
        #pragma unroll
        for (int nl = 0; nl < 3; ++nl) {
            const int l = nl * 16 + ln16;
            if (l < L_N) {
                const float iv = inv2[nl];
                #pragma unroll
                for (int md = 0; md < 2; ++md) {
                    const int db = ch * 32 + md * 16 + q * 4;   // 4 consecutive d
                    const s16x4 cv = *(const s16x4*)(bc + l * D_N + db);
                    s16x4 ov;
                    #pragma unroll
                    for (int j = 0; j < 4; ++j) {
                        float dv = a2[md][nl][j] * iv - bs2f((unsigned short)cv[j]);
                        ov[j] = (short)f2bs(dv * dv);
                    }
                    __builtin_nontemporal_store(ov, (s16x4*)(so + l * D_N + db));
                }
            }
        }
    }
}

// ---------------- B: GEMM3  out = l2norm(relu(sim @ W + b)) * mask ----------------
// M=163840, K=1024, N=256. Tile 128x256, BK=64, 8 waves (2 M-groups x 4 N-groups).
__global__ __launch_bounds__(512, 4)
void k_gemm3(const unsigned short* __restrict__ simg,
             const unsigned short* __restrict__ wt,
             const int* __restrict__ cap_lens,
             const float* __restrict__ bias,
             float* __restrict__ out) {
    __shared__ __align__(16) unsigned short sA[128 * 64];   // 16 KB, XOR-swizzled cols
    __shared__ __align__(16) unsigned short sB[256 * 64];   // 32 KB
    __shared__ float s_sum[128];

    const int tid = threadIdx.x;
    const int w = tid >> 6, lane = tid & 63;
    const int ln16 = lane & 15, q = lane >> 4;
    const int wm = (w >> 2) * 64, wn = (w & 3) * 64;
    const int m0 = blockIdx.x * 128;
    const int cgg = ((lane & 7) ^ (lane >> 3)) << 3;   // swizzled source col (shorts)
    const int lrow8 = lane >> 3;
    const int rx = ln16 & 7;

    if (tid < 128) s_sum[tid] = 0.f;

    f4 acc[4][4] = {};
    #pragma unroll 1
    for (int kc = 0; kc < 16; ++kc) {
        const int kofs = kc * 64;
        #pragma unroll
        for (int it = 0; it < 2; ++it) {
            int row = it * 64 + w * 8 + lrow8;
            async16(simg + (size_t)(m0 + row) * D_N + kofs + cgg,
                    sA + (it * 512 + w * 64) * 8);
        }
        #pragma unroll
        for (int it = 0; it < 4; ++it) {
            int row = it * 64 + w * 8 + lrow8;
            async16(wt + (size_t)row * D_N + kofs + cgg,
                    sB + (it * 512 + w * 64) * 8);
        }
        __syncthreads();
        #pragma unroll
        for (int ks = 0; ks < 2; ++ks) {
            const int g = ks * 4 + q;
            s16x8 af[4], bf[4];
            #pragma unroll
            for (int mt = 0; mt < 4; ++mt) {
                int row = wm + mt * 16 + ln16;
                af[mt] = *(const s16x8*)(sA + row * 64 + ((g ^ rx) << 3));
            }
            #pragma unroll
            for (int nt = 0; nt < 4; ++nt) {
                int row = wn + nt * 16 + ln16;
                bf[nt] = *(const s16x8*)(sB + row * 64 + ((g ^ rx) << 3));
            }
            #pragma unroll
            for (int mt = 0; mt < 4; ++mt)
                #pragma unroll
                for (int nt = 0; nt < 4; ++nt)
                    acc[mt][nt] = __builtin_amdgcn_mfma_f32_16x16x32_bf16(af[mt], bf[nt], acc[mt][nt], 0, 0, 0);
        }
        __syncthreads();
    }

    // epilogue: +bias, relu, sumsq over s (cross-wave LDS), l2norm, mask, store
    float bv[4];
    #pragma unroll
    for (int nt = 0; nt < 4; ++nt) bv[nt] = bias[wn + nt * 16 + ln16];
    #pragma unroll
    for (int mt = 0; mt < 4; ++mt)
        #pragma unroll
        for (int j = 0; j < 4; ++j) {
            float s = 0.f;
            #pragma unroll
            for (int nt = 0; nt < 4; ++nt) {
                float v = acc[mt][nt][j] + bv[nt];
                v = fmaxf(v, 0.f);
                acc[mt][nt][j] = v;
                s += v * v;
            }
            #pragma unroll
            for (int o = 1; o < 16; o <<= 1) s += __shfl_xor(s, o, 64);
            if (ln16 == 0) atomicAdd(&s_sum[wm + mt * 16 + q * 4 + j], s);
        }
    __syncthreads();
    if (tid < 128) {
        int grow = m0 + tid;
        int c = grow / (I_N * L_N);
        int l = grow % L_N;
        float inv = 1.f / (sqrtf(s_sum[tid]) + 1e-8f);
        s_sum[tid] = (l < cap_lens[c]) ? inv : 0.f;
    }
    __syncthreads();
    #pragma unroll
    for (int mt = 0; mt < 4; ++mt)
        #pragma unroll
        for (int j = 0; j < 4; ++j) {
            const int rt = wm + mt * 16 + q * 4 + j;
            const float sc = s_sum[rt];
            #pragma unroll
            for (int nt = 0; nt < 4; ++nt)
                __builtin_nontemporal_store(acc[mt][nt][j] * sc,
                    &out[(size_t)(m0 + rt) * S_N + wn + nt * 16 + ln16]);
        }
}

extern "C" void kernel_launch(void* const* d_in, const int* in_sizes, int n_in,
                              void* d_out, int out_size, void* d_ws, size_t ws_size,
                              hipStream_t stream) {
    const float* img  = (const float*)d_in[0];
    const float* cap  = (const float*)d_in[1];
    const int*   lens = (const int*)d_in[2];
    const float* W    = (const float*)d_in[5];
    const float* bias = (const float*)d_in[6];
    float* out = (float*)d_out;
    unsigned short* ws = (unsigned short*)d_ws;

    k_convert<<<10240, 256, 0, stream>>>(img, cap, W, ws);

    dim3 gridP(8, I_N);   // 512 blocks; kernel decodes (oct,i) with XCD-tile remap
    k_pre<<<gridP, 512, 0, stream>>>(ws, ws + OFF_CAP, ws + OFF_IMT, ws + OFF_SIM);

    k_gemm3<<<M_ALL / 128, 512, 0, stream>>>(ws + OFF_SIM, ws + OFF_WT, lens, bias, out);
}